// Round 10
// baseline (125.441 us; speedup 1.0000x reference)
//
#include <hip/hip_runtime.h>

#define BS        64
#define W_TOTAL_C 2234368
#define B_TOTAL_C 3526

__device__ __forceinline__ float silu_f(float v) {
    return v / (1.f + __expf(-v));
}

// ---------------------------------------------------------------------------
// One layer, split-K, NO cross-block sync:
//   - stage h-chunk into LDS; if PNK>0, h is reconstructed as
//     silu( sum_{k<PNK} prev_part[k][b][i] + prev_bias[i] )
//   - K-loop: a[j] += sh[i] * W[b][k0+i][o+j]   (coalesced float2 weight loads)
//   - if FINAL: write tanh(a + bias) straight to d_out
//     else:     write raw partial to this layer's slice (plain stores)
// Visibility across layers comes from kernel boundaries on the stream.
template<int DIN, int DOUT, int KC, int NK, int PNK, int VEC, int BLK,
         bool FINAL, int WOFF, int PBOFF, int FBOFF>
__global__ __launch_bounds__(BLK)
void layer_kernel(const float* __restrict__ hin,   // x (PNK==0) or prev partials
                  const float* __restrict__ wbase,
                  const float* __restrict__ bias,
                  float* __restrict__ outp)        // this layer's partials, or d_out
{
    __shared__ float sh[KC];

    const int b   = blockIdx.z;
    const int ky  = blockIdx.y;
    const int k0  = ky * KC;
    const int tid = threadIdx.x;

    // ---- stage h chunk (fuse prev layer's reduction + bias + silu) ----
    for (int i = tid; i < KC; i += BLK) {
        float s;
        if (PNK == 0) {
            s = hin[b * DIN + k0 + i];
        } else {
            s = bias[b * B_TOTAL_C + PBOFF + k0 + i];
            #pragma unroll
            for (int k = 0; k < PNK; ++k)
                s += hin[((size_t)k * BS + b) * DIN + k0 + i];
            s = silu_f(s);
        }
        sh[i] = s;
    }
    __syncthreads();

    const int  o      = (blockIdx.x * BLK + tid) * VEC;
    const bool active = (o < DOUT);

    float a0 = 0.f, a1 = 0.f;
    if (active) {
        const float* wp = wbase + (size_t)b * W_TOTAL_C + WOFF
                                + (size_t)k0 * DOUT + o;
        #pragma unroll 16
        for (int i = 0; i < KC; ++i) {
            const float hv = sh[i];
            const float2 w = *reinterpret_cast<const float2*>(wp);
            a0 = fmaf(hv, w.x, a0);
            a1 = fmaf(hv, w.y, a1);
            wp += DOUT;
        }
    }

    if (!active) return;

    if (FINAL) {
        float v0 = a0 + bias[b * B_TOTAL_C + FBOFF + o];
        outp[b * DOUT + o] = tanhf(v0);
        if (o + 1 < DOUT) {
            float v1 = a1 + bias[b * B_TOTAL_C + FBOFF + o + 1];
            outp[b * DOUT + o + 1] = tanhf(v1);
        }
    } else {
        float* pp = outp + ((size_t)ky * BS + b) * DOUT + o;
        pp[0] = a0;
        pp[1] = a1;
    }
}

// ---------------------------------------------------------------------------
// final reduce: out[b][o] = tanh( sum_{k<4} part[k][b][o] + bias[b][1664+o] )
__global__ __launch_bounds__(256)
void reduce_tanh_kernel(const float* __restrict__ part,
                        const float* __restrict__ bias,
                        float* __restrict__ out)
{
    const int b  = blockIdx.y;
    const int o2 = blockIdx.x * 256 + threadIdx.x;   // float2 index, 931 per b
    if (o2 >= 931) return;
    const int o = o2 * 2;
    float2 s = *reinterpret_cast<const float2*>(&bias[b * B_TOTAL_C + 1664 + o]);
    #pragma unroll
    for (int k = 0; k < 4; ++k) {
        const float2 p = *reinterpret_cast<const float2*>(
            &part[((size_t)k * BS + b) * 1862 + o]);
        s.x += p.x;
        s.y += p.y;
    }
    float2 r;
    r.x = tanhf(s.x);
    r.y = tanhf(s.y);
    *reinterpret_cast<float2*>(&out[b * 1862 + o]) = r;
}

// ---------------------------------------------------------------------------
extern "C" void kernel_launch(void* const* d_in, const int* in_sizes, int n_in,
                              void* d_out, int out_size, void* d_ws, size_t ws_size,
                              hipStream_t stream)
{
    const float* x    = (const float*)d_in[0];   // [64][1862]
    const float* wts  = (const float*)d_in[1];   // [64][W_TOTAL]
    const float* bias = (const float*)d_in[2];   // [64][B_TOTAL]
    float* out = (float*)d_out;                  // [64][1862]

    // partial slices (floats), all plain-store/plain-load, written before read
    float* p0 = (float*)d_ws;        // 7*64*512  = 229376
    float* p1 = p0 + 229376;         // 4*64*256  =  65536
    float* p2 = p1 + 65536;          // 4*64*128  =  32768
    float* p3 = p2 + 32768;          // 4*64*256  =  65536
    float* p4 = p3 + 65536;          // 4*64*512  = 131072
    float* p5 = p4 + 131072;         // 4*64*1862 = 476672  (total ~4.0 MB)

    // L0: 1862 -> 512   (reads x; writes p0)       grid 2x7x64 = 896 blocks
    layer_kernel<1862, 512, 266, 7, 0, 2, 128, false,       0,    0,    0>
        <<<dim3(2, 7, BS), 128, 0, stream>>>(x, wts, bias, p0);
    // L1: 512 -> 256    (reduce p0 + silu; writes p1)  grid 1x4x64 = 256
    layer_kernel< 512, 256, 128, 4, 7, 2, 128, false,  953344,    0,    0>
        <<<dim3(1, 4, BS), 128, 0, stream>>>(p0, wts, bias, p1);
    // L2: 256 -> 128    (reduce p1; writes p2)          grid 1x4x64 = 256
    layer_kernel< 256, 128,  64, 4, 4, 2,  64, false, 1084416,  512,    0>
        <<<dim3(1, 4, BS),  64, 0, stream>>>(p1, wts, bias, p2);
    // L3: 128 -> 256    (reduce p2; writes p3)          grid 1x4x64 = 256
    layer_kernel< 128, 256,  32, 4, 4, 2, 128, false, 1117184,  768,    0>
        <<<dim3(1, 4, BS), 128, 0, stream>>>(p2, wts, bias, p3);
    // L4: 256 -> 512    (reduce p3; writes p4)          grid 2x4x64 = 512
    layer_kernel< 256, 512,  64, 4, 4, 2, 128, false, 1149952,  896,    0>
        <<<dim3(2, 4, BS), 128, 0, stream>>>(p3, wts, bias, p4);
    // L5a: 512 -> 1862  SPLIT-K NK=4 (reduce p4; writes p5)
    //      grid 8x4x64 = 2048 blocks = 4096 waves (16/CU) — latency fix
    layer_kernel< 512, 1862, 128, 4, 4, 2, 128, false, 1281024, 1152,    0>
        <<<dim3(8, 4, BS), 128, 0, stream>>>(p4, wts, bias, p5);
    // L5b: reduce 4 partials + bias + tanh -> d_out     grid 4x64 = 256 blocks
    reduce_tanh_kernel<<<dim3(4, BS), 256, 0, stream>>>(p5, bias, out);
}

// Round 11
// 120.621 us; speedup vs baseline: 1.0400x; 1.0400x over previous
//
#include <hip/hip_runtime.h>

#define BS        64
#define W_TOTAL_C 2234368
#define B_TOTAL_C 3526

__device__ __forceinline__ float silu_f(float v) {
    return v / (1.f + __expf(-v));
}

// ---------------------------------------------------------------------------
// One layer, split-K, NO cross-block sync:
//   - stage h-chunk into LDS; if PNK>0, h is reconstructed as
//     silu( sum_{k<PNK} prev_part[k][b][i] + prev_bias[i] )
//   - K-loop: a[j] += sh[i] * W[b][k0+i][o+j]
//     VEC=2: float2 loads (any even DOUT). VEC=4: float4 loads — ONLY for
//     DOUT%4==0 (16B-aligned rows) with exact coverage.
//   - if FINAL: write tanh(a + bias) straight to d_out
//     else:     write raw partial to this layer's slice (plain stores)
// Visibility across layers comes from kernel boundaries on the stream.
template<int DIN, int DOUT, int KC, int NK, int PNK, int VEC, int BLK,
         bool FINAL, int WOFF, int PBOFF, int FBOFF>
__global__ __launch_bounds__(BLK)
void layer_kernel(const float* __restrict__ hin,   // x (PNK==0) or prev partials
                  const float* __restrict__ wbase,
                  const float* __restrict__ bias,
                  float* __restrict__ outp)        // this layer's partials, or d_out
{
    __shared__ float sh[KC];

    const int b   = blockIdx.z;
    const int ky  = blockIdx.y;
    const int k0  = ky * KC;
    const int tid = threadIdx.x;

    // ---- stage h chunk (fuse prev layer's reduction + bias + silu) ----
    for (int i = tid; i < KC; i += BLK) {
        float s;
        if (PNK == 0) {
            s = hin[b * DIN + k0 + i];
        } else {
            s = bias[b * B_TOTAL_C + PBOFF + k0 + i];
            #pragma unroll
            for (int k = 0; k < PNK; ++k)
                s += hin[((size_t)k * BS + b) * DIN + k0 + i];
            s = silu_f(s);
        }
        sh[i] = s;
    }
    __syncthreads();

    const int  o      = (blockIdx.x * BLK + tid) * VEC;
    const bool active = (o < DOUT);

    float a0 = 0.f, a1 = 0.f, a2 = 0.f, a3 = 0.f;
    if (active) {
        const float* wp = wbase + (size_t)b * W_TOTAL_C + WOFF
                                + (size_t)k0 * DOUT + o;
        if (VEC == 4) {
            #pragma unroll 16
            for (int i = 0; i < KC; ++i) {
                const float hv = sh[i];
                const float4 w = *reinterpret_cast<const float4*>(wp);
                a0 = fmaf(hv, w.x, a0);
                a1 = fmaf(hv, w.y, a1);
                a2 = fmaf(hv, w.z, a2);
                a3 = fmaf(hv, w.w, a3);
                wp += DOUT;
            }
        } else {
            #pragma unroll 16
            for (int i = 0; i < KC; ++i) {
                const float hv = sh[i];
                const float2 w = *reinterpret_cast<const float2*>(wp);
                a0 = fmaf(hv, w.x, a0);
                a1 = fmaf(hv, w.y, a1);
                wp += DOUT;
            }
        }
    }

    if (!active) return;

    if (FINAL) {
        float v0 = a0 + bias[b * B_TOTAL_C + FBOFF + o];
        outp[b * DOUT + o] = tanhf(v0);
        if (o + 1 < DOUT) {
            float v1 = a1 + bias[b * B_TOTAL_C + FBOFF + o + 1];
            outp[b * DOUT + o + 1] = tanhf(v1);
        }
    } else {
        float* pp = outp + ((size_t)ky * BS + b) * DOUT + o;
        if (VEC == 4) {
            *reinterpret_cast<float4*>(pp) = make_float4(a0, a1, a2, a3);
        } else {
            pp[0] = a0;
            pp[1] = a1;
        }
    }
}

// ---------------------------------------------------------------------------
extern "C" void kernel_launch(void* const* d_in, const int* in_sizes, int n_in,
                              void* d_out, int out_size, void* d_ws, size_t ws_size,
                              hipStream_t stream)
{
    const float* x    = (const float*)d_in[0];   // [64][1862]
    const float* wts  = (const float*)d_in[1];   // [64][W_TOTAL]
    const float* bias = (const float*)d_in[2];   // [64][B_TOTAL]
    float* out = (float*)d_out;                  // [64][1862]

    // partial slices (floats), all plain-store/plain-load, written before read
    float* p0 = (float*)d_ws;        // 7*64*512  = 229376
    float* p1 = p0 + 229376;         // 4*64*256  =  65536
    float* p2 = p1 + 65536;          // 4*64*128  =  32768
    float* p3 = p2 + 32768;          // 4*64*256  =  65536
    float* p4 = p3 + 65536;          // 4*64*512  = 131072  (total 524288 f = 2 MB)

    // L0: 1862 -> 512   (reads x; writes p0)  VEC=4 (16B-aligned rows),
    //     grid 1x7x64 = 448 blocks x 2 waves; exact coverage 128*4 = 512
    layer_kernel<1862, 512, 266, 7, 0, 4, 128, false,       0,    0,    0>
        <<<dim3(1, 7, BS), 128, 0, stream>>>(x, wts, bias, p0);
    // L1: 512 -> 256    (reduce p0 + silu; writes p1)  grid 1x4x64 = 256
    layer_kernel< 512, 256, 128, 4, 7, 2, 128, false,  953344,    0,    0>
        <<<dim3(1, 4, BS), 128, 0, stream>>>(p0, wts, bias, p1);
    // L2: 256 -> 128    (reduce p1; writes p2)          grid 1x4x64 = 256
    layer_kernel< 256, 128,  64, 4, 4, 2,  64, false, 1084416,  512,    0>
        <<<dim3(1, 4, BS),  64, 0, stream>>>(p1, wts, bias, p2);
    // L3: 128 -> 256    (reduce p2; writes p3)          grid 1x4x64 = 256
    layer_kernel< 128, 256,  32, 4, 4, 2, 128, false, 1117184,  768,    0>
        <<<dim3(1, 4, BS), 128, 0, stream>>>(p2, wts, bias, p3);
    // L4: 256 -> 512    (reduce p3; writes p4)          grid 2x4x64 = 512
    layer_kernel< 256, 512,  64, 4, 4, 2, 128, false, 1149952,  896,    0>
        <<<dim3(2, 4, BS), 128, 0, stream>>>(p3, wts, bias, p4);
    // L5: 512 -> 1862   (reduce p4; bias+tanh; writes d_out)  grid 8x1x64 = 512
    layer_kernel< 512, 1862, 512, 1, 4, 2, 128, true, 1281024, 1152, 1664>
        <<<dim3(8, 1, BS), 128, 0, stream>>>(p4, wts, bias, out);
}